// Round 1
// baseline (147.978 us; speedup 1.0000x reference)
//
#include <hip/hip_runtime.h>

// SigMMDLoss, algebraically flattened (see round-1/2 derivation):
//   A  = p[4095]-p[0]; S3 = p[4095] - SP_row/n; S4 = (A^2+S6)/2;
//   S6 = sum d^2; S8 = sum d^3;  time-only features cancel.
// Global sums per array: SP (sum p excl last col), D2, D3,
// G1 = sum_rows A, G2 = sum_rows A^2, G3 = sum_rows p[4095].
// out = sum_q ((F_q^real - F_q^gen)/B)^2.
//
// Round-4 structure: latency-bound fix. One wave = one 2048-elem row
// segment (16384 waves total, 2x previous). Zero cross-lane ops in the
// hot path: the predecessor element p[idx-1] is loaded directly as one
// extra dword per float4 (same cache lines -> L1/MSHR hit, no extra HBM
// traffic) instead of shfl_up/carry-broadcast ds_bpermute chains.
// __launch_bounds__(256,8) pins <=64 VGPR -> 8 waves/SIMD.

constexpr int T_LEN = 4096;
constexpr int B_ROWS = 4096;
constexpr int NQ = 6;                   // sp, d2, d3, g1, g2, g3
constexpr int NBLK = 2048;              // blocks per `which` (grid.x)
constexpr int PSTR = 2 * NBLK;          // 4096 partial slots per quantity

__global__ __launch_bounds__(256, 8) void sig_flat3(
    const float* __restrict__ real, const float* __restrict__ gen,
    double* __restrict__ P) {
  const int tid = threadIdx.x;
  const int lane = tid & 63;
  const int wid = tid >> 6;
  const int which = blockIdx.y;
  const int row = blockIdx.x * 2 + (wid >> 1);   // 2 rows per block
  const int seg = wid & 1;                       // 0: [0,2048)  1: [2048,4096)
  const float* __restrict__ rp = (which ? gen : real) + (size_t)row * T_LEN;
  const int off = seg * 2048;

  // 8 coalesced float4 loads (1 KB/wave/instr), all batched in flight.
  const float4* __restrict__ q4 = reinterpret_cast<const float4*>(rp + off);
  float4 a[8];
#pragma unroll
  for (int j = 0; j < 8; ++j) a[j] = q4[j * 64 + lane];

  // Predecessor element of each float4 (p[idx-1]); same lines as above,
  // L1/MSHR-merged. Clamp only bites at row element 0 (d0 = 0 there).
  float pv[8];
  const int em1 = off + 4 * lane - 1;
#pragma unroll
  for (int j = 0; j < 8; ++j) {
    const int e = em1 + j * 256;
    pv[j] = rp[e < 0 ? 0 : e];
  }
  const float p0 = rp[0];               // row head; L1-hot (same block)

  float sp = 0.f, s2 = 0.f, s3 = 0.f;
#pragma unroll
  for (int j = 0; j < 8; ++j) {
    const float d0 = a[j].x - pv[j];
    const float d1 = a[j].y - a[j].x;
    const float d2 = a[j].z - a[j].y;
    const float d3 = a[j].w - a[j].z;
    const float e0 = d0 * d0, e1 = d1 * d1, e2 = d2 * d2, e3 = d3 * d3;
    s2 += (e0 + e1) + (e2 + e3);
    s3 += (e0 * d0 + e1 * d1) + (e2 * d2 + e3 * d3);
    sp += (a[j].x + a[j].y) + (a[j].z + a[j].w);
  }

  // Row-level features on the tail segment's last lane (holds p[4095]).
  double g1 = 0., g2 = 0., g3 = 0.;
  if ((seg == 1) && (lane == 63)) {
    const float plast = a[7].w;         // p[4095]
    sp -= plast;                        // SP excludes last column
    const double A = (double)plast - (double)p0;
    g1 = A;
    g2 = A * A;
    g3 = (double)plast;
  }

  // Wave reduce (fp32 streams; g* already single-lane).
#pragma unroll
  for (int o = 32; o; o >>= 1) {
    sp += __shfl_down(sp, o, 64);
    s2 += __shfl_down(s2, o, 64);
    s3 += __shfl_down(s3, o, 64);
  }

  __shared__ double sred[4][NQ];
  if (lane == 0) {
    sred[wid][0] = (double)sp;
    sred[wid][1] = (double)s2;
    sred[wid][2] = (double)s3;
  }
  if (lane == 63) {                     // seg0 waves write zeros (harmless)
    sred[wid][3] = g1;
    sred[wid][4] = g2;
    sred[wid][5] = g3;
  }
  __syncthreads();
  if (tid < NQ) {
    const double s = sred[0][tid] + sred[1][tid] + sred[2][tid] + sred[3][tid];
    P[tid * PSTR + which * NBLK + blockIdx.x] = s;
  }
}

__global__ __launch_bounds__(1024) void sig_final(const double* __restrict__ P,
                                                  float* __restrict__ out) {
  const int tid = threadIdx.x;
  double loc[NQ] = {0, 0, 0, 0, 0, 0};
  for (int i = tid; i < NBLK; i += 1024) {
#pragma unroll
    for (int q = 0; q < NQ; ++q)
      loc[q] += P[q * PSTR + i] - P[q * PSTR + NBLK + i];
  }
#pragma unroll
  for (int q = 0; q < NQ; ++q)
#pragma unroll
    for (int o = 32; o; o >>= 1) loc[q] += __shfl_down(loc[q], o, 64);

  __shared__ double sred[16][NQ];
  const int lane = tid & 63, wid = tid >> 6;
  if (lane == 0)
#pragma unroll
    for (int q = 0; q < NQ; ++q) sred[wid][q] = loc[q];
  __syncthreads();
  if (tid == 0) {
    double Q[NQ];
#pragma unroll
    for (int q = 0; q < NQ; ++q) {
      double s = 0.;
      for (int w = 0; w < 16; ++w) s += sred[w][q];
      Q[q] = s;
    }
    const double n = (double)(T_LEN - 1), Bn = (double)B_ROWS;
    const double FA = Q[3] / Bn;
    const double FS3 = (Q[5] - Q[0] / n) / Bn;
    const double FS4 = 0.5 * (Q[4] + Q[1]) / Bn;
    const double FS6 = Q[1] / Bn;
    const double FS8 = Q[2] / Bn;
    const double o = FA * FA + FS3 * FS3 + FS4 * FS4 + FS6 * FS6 + FS8 * FS8;
    out[0] = (float)o;
  }
}

extern "C" void kernel_launch(void* const* d_in, const int* in_sizes, int n_in,
                              void* d_out, int out_size, void* d_ws, size_t ws_size,
                              hipStream_t stream) {
  const float* real = (const float*)d_in[0];
  const float* gen = (const float*)d_in[1];
  double* P = (double*)d_ws;            // NQ * PSTR * 8 = 192 KB
  float* out = (float*)d_out;

  dim3 grid(NBLK, 2);
  sig_flat3<<<grid, 256, 0, stream>>>(real, gen, P);
  sig_final<<<1, 1024, 0, stream>>>(P, out);
}